// Round 2
// 246.540 us; speedup vs baseline: 1.0000x; 1.0000x over previous
//
#include <hip/hip_runtime.h>

// out[n,c,h,w] = sum_{c'} g[(c-c') mod 128] * act[n,c',h,w]
// where g = ifft(1 / fft(delta - k)), k = rolled zero-padded Ricker filter.
// C=128, S=H*W=4096 per image, 64 images.
//
// Rev 2: fixes rev-1 staging bug (load offset was (16p+i)*4096 instead of
// (64p+i)*4096 -> channel permutation). Structure unchanged:
// (1) staging via register micro-transpose -> ds_write_b128 into an
//     XOR-swizzled [s][c'] bf16 tile (kills the 16-way scalar-write conflicts
//     that were 33% of kernel cycles in the 83us baseline);
// (2) MFMA operands: A = X^T frags (LDS), B = circulant-G frags (regs), so
//     D[m=s][n=c] gives float4 epilogue stores (4x fewer store instrs).

typedef short bf16x8 __attribute__((ext_vector_type(8)));
typedef float f32x4 __attribute__((ext_vector_type(4)));

#define MFMA16x16x32 __builtin_amdgcn_mfma_f32_16x16x32_bf16

__device__ __forceinline__ unsigned short f2bf_rne(float f) {
  union { float f; unsigned u; } v; v.f = f;
  unsigned u = v.u;
  u += 0x7fffu + ((u >> 16) & 1u);   // round-to-nearest-even
  return (unsigned short)(u >> 16);
}

// ---------------------------------------------------------------------------
// Setup: compute g[128] as bf16 from the 27-tap filter. One block, 128 thr.
// kf[j] = filt[t] at j=(115+t)&127 (pad_left=50, roll by 65).
// Fk[m] = 1 - sum_t kf*e^{-2pi i j m/128};  g[n] = (1/128) Re sum_m e^{+2pi i mn/128}/Fk[m]
// ---------------------------------------------------------------------------
__global__ void build_g(const float* __restrict__ filt,
                        unsigned short* __restrict__ gbf) {
  __shared__ float ct[128], st[128], fr[128], fi[128];
  const int t = threadIdx.x;  // 0..127
  const float ang = (float)t * 0.049087385212340526f;  // 2*pi/128
  float s, c;
  __sincosf(ang, &s, &c);
  ct[t] = c; st[t] = s;
  __syncthreads();

  // forward DFT of (delta - kf) at frequency m=t
  float re = 1.f, im = 0.f;
  for (int tt = 0; tt < 27; ++tt) {
    const int j = (115 + tt) & 127;
    const int idx = (j * t) & 127;
    const float kv = filt[tt];
    re -= kv * ct[idx];   // e^{-i a} = cos a - i sin a
    im += kv * st[idx];
  }
  fr[t] = re; fi[t] = im;
  __syncthreads();

  // inverse DFT of 1/Fk at position n=t (real part)
  float acc = 0.f;
  for (int m = 0; m < 128; ++m) {
    const int idx = (m * t) & 127;
    const float dr = fr[m], di = fi[m];
    acc += (ct[idx] * dr + st[idx] * di) / (dr * dr + di * di);
  }
  gbf[t] = f2bf_rne(acc * (1.0f / 128.0f));
}

// ---------------------------------------------------------------------------
// Main kernel: per block (256 thr = 4 waves): one image n, one 128-wide s-tile.
// GEMM orientation: D[m=s][n=c_out] = sum_{k=c'} X^T[s][c'] * G[c'][c_out].
//   A-operand = X^T fragments from swizzled LDS tile (ds_read_b128)
//   B-operand = G fragments, G[c'][c_out] = g[(c_out-c')&127] (registers)
//   D layout: col=lane&15 (c_out), row=quad*4+reg (s) -> float4 stores.
// Wave w owns c_out in [32w, 32w+32): 8 persistent B-frags, acc = 8mt x 2nt.
//
// LDS layout Xt: bf16 element (s, c') at short index
//   s*128 + (((c'>>3) ^ (s&7))<<3) + (c'&7)
// XOR swizzle makes both ds_write_b128 (staging) and ds_read_b128 (A-frags)
// hit the b128 bank-cycle minimum.
// ---------------------------------------------------------------------------
__global__ __launch_bounds__(256, 4) void conv_inhib(
    const float* __restrict__ X, const unsigned short* __restrict__ gtab,
    float* __restrict__ Y) {
  __shared__ __align__(16) unsigned short Xt[128 * 128];  // 32 KB
  __shared__ unsigned short gsh[128];

  const int tid = threadIdx.x;
  const int l = tid & 63;        // lane in wave
  const int w = tid >> 6;        // wave id 0..3
  const int lane15 = l & 15;
  const int quad = l >> 4;

  const int bid = blockIdx.x;          // 0..2047
  const int nimg = bid >> 5;           // 0..63
  const int s0 = (bid & 31) << 7;      // s-tile origin (128 cols)
  const float* Xn = X + (size_t)nimg * (128 * 4096);
  float* Yn = Y + (size_t)nimg * (128 * 4096);

  if (tid < 128) gsh[tid] = gtab[tid];

  // ---- Stage X tile ----
  // Thread (cb=tid&7, sg=tid>>3) covers channels {64p + 8cb + i, i=0..7} for
  // p=0,1 and s_local in {4sg..4sg+3}. Coalesced f32x4 loads (8 lanes x 16B
  // = 128 B runs per channel), register 8x4 transpose, ds_write_b128.
  {
    const int cb = tid & 7;
    const int sg = tid >> 3;  // 0..31
    const float* src = Xn + (size_t)(cb << 3) * 4096 + s0 + (sg << 2);
    f32x4 v[16];
#pragma unroll
    for (int p = 0; p < 2; ++p)
#pragma unroll
      for (int i = 0; i < 8; ++i)
        v[(p << 3) + i] = *(const f32x4*)(src + (size_t)((p << 6) + i) * 4096);
#pragma unroll
    for (int p = 0; p < 2; ++p) {
      const int chunk = cb + (p << 3);  // c-group index c0>>3, 0..15
#pragma unroll
      for (int j = 0; j < 4; ++j) {
        const int s = (sg << 2) + j;
        bf16x8 t;
#pragma unroll
        for (int i = 0; i < 8; ++i) t[i] = (short)f2bf_rne(v[(p << 3) + i][j]);
        *(bf16x8*)&Xt[(s << 7) + ((chunk ^ (s & 7)) << 3)] = t;
      }
    }
  }
  __syncthreads();

  // ---- Persistent B fragments: B[k=c'][n=c_out] = g[(c_out - c') & 127] ----
  // layout: lane holds n=lane&15, k=quad*8+j within each 32-wide k-block kk.
  bf16x8 bfrag[2][4];
#pragma unroll
  for (int nt = 0; nt < 2; ++nt) {
    const int cout = (w << 5) + (nt << 4) + lane15;
#pragma unroll
    for (int kk = 0; kk < 4; ++kk) {
      const int kb = (kk << 5) + (quad << 3);
#pragma unroll
      for (int j = 0; j < 8; ++j)
        bfrag[nt][kk][j] = (short)gsh[(cout - kb - j) & 127];
    }
  }

  // ---- GEMM: acc[mt][nt] over all 8 s-subtiles, K=128 ----
  f32x4 acc[8][2];
#pragma unroll
  for (int mt = 0; mt < 8; ++mt)
#pragma unroll
    for (int nt = 0; nt < 2; ++nt)
      acc[mt][nt] = (f32x4){0.f, 0.f, 0.f, 0.f};

#pragma unroll
  for (int mt = 0; mt < 8; ++mt) {
    const int srow = (mt << 4) + lane15;
    const int rb = srow << 7;
    const int sx = srow & 7;
#pragma unroll
    for (int kk = 0; kk < 4; ++kk) {
      const bf16x8 a = *(const bf16x8*)&Xt[rb + ((((kk << 2) + quad) ^ sx) << 3)];
      acc[mt][0] = MFMA16x16x32(a, bfrag[0][kk], acc[mt][0], 0, 0, 0);
      acc[mt][1] = MFMA16x16x32(a, bfrag[1][kk], acc[mt][1], 0, 0, 0);
    }
  }

  // ---- Epilogue: D row = quad*4+reg = s-within-16 -> float4 stores ----
#pragma unroll
  for (int nt = 0; nt < 2; ++nt) {
    const int c = (w << 5) + (nt << 4) + lane15;
    float* Yc = Yn + (size_t)c * 4096 + s0 + (quad << 2);
#pragma unroll
    for (int mt = 0; mt < 8; ++mt) {
      *(f32x4*)(Yc + (mt << 4)) = acc[mt][nt];
    }
  }
}

extern "C" void kernel_launch(void* const* d_in, const int* in_sizes, int n_in,
                              void* d_out, int out_size, void* d_ws, size_t ws_size,
                              hipStream_t stream) {
  const float* act = (const float*)d_in[0];   // (64,128,64,64) fp32
  const float* filt = (const float*)d_in[1];  // 27 fp32
  float* out = (float*)d_out;                 // (64,128,64,64) fp32
  unsigned short* g = (unsigned short*)d_ws;  // 128 bf16 scratch

  build_g<<<1, 128, 0, stream>>>(filt, g);
  conv_inhib<<<2048, 256, 0, stream>>>(act, g, out);
}